// Round 1
// baseline (508.230 us; speedup 1.0000x reference)
//
#include <hip/hip_runtime.h>

#define NUM_CLASSES 80
#define N13 507
#define N26 2028
#define N52 8112
#define NANCH (N13 + N26 + N52)   // 10647
#define BATCH 64
#define NEGV  (-1e9f)
#define THREADS 1024
#define K 11                       // ceil(10647/1024)
#define MAXB 100

// ---------------- Phase 1: per-anchor score = p * (float)argmax(classes) ----------------
__global__ __launch_bounds__(256) void score_kernel(
    const float* __restrict__ c13, const float* __restrict__ p13,
    const float* __restrict__ c26, const float* __restrict__ p26,
    const float* __restrict__ c52, const float* __restrict__ p52,
    float* __restrict__ scores)
{
    int n = blockIdx.x * blockDim.x + threadIdx.x;
    int b = blockIdx.y;
    if (n >= NANCH) return;
    const float* cbase; const float* pbase;
    if (n < N13)            { cbase = c13 + ((size_t)b*N13 + n) * NUM_CLASSES;              pbase = p13 + (size_t)b*N13 + n; }
    else if (n < N13+N26)   { cbase = c26 + ((size_t)b*N26 + (n-N13)) * NUM_CLASSES;        pbase = p26 + (size_t)b*N26 + (n-N13); }
    else                    { cbase = c52 + ((size_t)b*N52 + (n-N13-N26)) * NUM_CLASSES;    pbase = p52 + (size_t)b*N52 + (n-N13-N26); }
    const float4* cp = (const float4*)cbase;
    float mx = -1.0f; int mi = 0;
    #pragma unroll
    for (int q = 0; q < NUM_CLASSES/4; ++q) {
        float4 v = cp[q];
        if (v.x > mx) { mx = v.x; mi = 4*q+0; }   // strict > keeps FIRST max (jnp.argmax)
        if (v.y > mx) { mx = v.y; mi = 4*q+1; }
        if (v.z > mx) { mx = v.z; mi = 4*q+2; }
        if (v.w > mx) { mx = v.w; mi = 4*q+3; }
    }
    scores[(size_t)b*NANCH + n] = pbase[0] * (float)mi;
}

// ---------------- Phase 2: greedy NMS, one block per batch ----------------
__device__ __forceinline__ float4 load_box(const float* __restrict__ b13,
                                           const float* __restrict__ b26,
                                           const float* __restrict__ b52,
                                           int b, int n)
{
    if (n < N13)          return *(const float4*)(b13 + ((size_t)b*N13 + n)*4);
    else if (n < N13+N26) return *(const float4*)(b26 + ((size_t)b*N26 + (n-N13))*4);
    else                  return *(const float4*)(b52 + ((size_t)b*N52 + (n-N13-N26))*4);
}

__global__ __launch_bounds__(THREADS) void nms_kernel(
    const float* __restrict__ scores,
    const float* __restrict__ b13, const float* __restrict__ b26, const float* __restrict__ b52,
    float* __restrict__ out)
{
    const int b   = blockIdx.x;
    const int tid = threadIdx.x;
    const int lane = tid & 63;
    const int wid  = tid >> 6;

    __shared__ float lv[THREADS/64];
    __shared__ int   ln[THREADS/64];
    __shared__ float bv_s;
    __shared__ int   bn_s;

    float s[K], y1[K], x1[K], y2[K], x2[K], ar[K];
    #pragma unroll
    for (int k = 0; k < K; ++k) {
        int n = tid + k*THREADS;
        if (n < NANCH) {
            float sc = scores[(size_t)b*NANCH + n];
            s[k] = (sc > 0.5f) ? sc : NEGV;       // strict >, matches reference
            float4 bb = load_box(b13,b26,b52,b,n);
            y1[k] = fminf(bb.x, bb.z); y2[k] = fmaxf(bb.x, bb.z);
            x1[k] = fminf(bb.y, bb.w); x2[k] = fmaxf(bb.y, bb.w);
            ar[k] = (y2[k]-y1[k])*(x2[k]-x1[k]);
        } else {
            s[k] = NEGV; y1[k]=x1[k]=y2[k]=x2[k]=ar[k]=0.f;
        }
    }

    float* outp = out + (size_t)b*(MAXB*6);
    int t = 0;
    for (; t < MAXB; ++t) {
        // --- distributed argmax, lowest-global-index tie-break ---
        float bv = NEGV; int bn = 0x7FFFFFFF;
        #pragma unroll
        for (int k = 0; k < K; ++k) {
            int n = tid + k*THREADS;
            if (s[k] > bv) { bv = s[k]; bn = n; }  // k ascending => lowest n wins ties
        }
        #pragma unroll
        for (int off = 32; off >= 1; off >>= 1) {
            float ov = __shfl_xor(bv, off);
            int   on = __shfl_xor(bn, off);
            if (ov > bv || (ov == bv && on < bn)) { bv = ov; bn = on; }
        }
        if (lane == 0) { lv[wid] = bv; ln[wid] = bn; }
        __syncthreads();
        if (tid == 0) {
            float fv = lv[0]; int fn = ln[0];
            #pragma unroll
            for (int w = 1; w < THREADS/64; ++w) {
                float v2 = lv[w]; int n2 = ln[w];
                if (v2 > fv || (v2 == fv && n2 < fn)) { fv = v2; fn = n2; }
            }
            bv_s = fv; bn_s = fn;
        }
        __syncthreads();
        const float V   = bv_s;
        const int  nsel = bn_s;
        if (!(V > 0.5f)) break;                    // invalidity is monotone -> rest are zeros

        // every thread loads the selected box (uniform address, L2 hit)
        float4 sb = load_box(b13,b26,b52,b,nsel);
        float sy1 = fminf(sb.x, sb.z), sy2 = fmaxf(sb.x, sb.z);
        float sx1 = fminf(sb.y, sb.w), sx2 = fmaxf(sb.y, sb.w);
        float sarea = (sy2-sy1)*(sx2-sx1);

        #pragma unroll
        for (int k = 0; k < K; ++k) {
            int n = tid + k*THREADS;
            float iy1 = fmaxf(y1[k], sy1), iy2 = fminf(y2[k], sy2);
            float ix1 = fmaxf(x1[k], sx1), ix2 = fminf(x2[k], sx2);
            float inter = fmaxf(iy2-iy1, 0.f) * fmaxf(ix2-ix1, 0.f);
            float un = (ar[k] + sarea) - inter;    // same op order as reference
            bool sup = (un > 0.f) && (inter/un > 0.5f);   // IEEE divide: bit-match ref
            if (sup || n == nsel) s[k] = NEGV;
        }

        if (tid == 0) {
            outp[t*6+0] = fminf(fmaxf(sb.x,0.f),1.f);
            outp[t*6+1] = fminf(fmaxf(sb.y,0.f),1.f);
            outp[t*6+2] = fminf(fmaxf(sb.z,0.f),1.f);
            outp[t*6+3] = fminf(fmaxf(sb.w,0.f),1.f);
            outp[t*6+4] = V;
            outp[t*6+5] = 0.f;
        }
    }
    // zero-fill remaining slots + write valid count (as float32)
    for (int i = t*6 + tid; i < MAXB*6; i += THREADS) outp[i] = 0.f;
    if (tid == 0) out[(size_t)BATCH*MAXB*6 + b] = (float)t;
}

extern "C" void kernel_launch(void* const* d_in, const int* in_sizes, int n_in,
                              void* d_out, int out_size, void* d_ws, size_t ws_size,
                              hipStream_t stream)
{
    const float* bbox13 = (const float*)d_in[0];
    const float* p13    = (const float*)d_in[1];
    const float* c13    = (const float*)d_in[2];
    const float* bbox26 = (const float*)d_in[3];
    const float* p26    = (const float*)d_in[4];
    const float* c26    = (const float*)d_in[5];
    const float* bbox52 = (const float*)d_in[6];
    const float* p52    = (const float*)d_in[7];
    const float* c52    = (const float*)d_in[8];
    float* out    = (float*)d_out;
    float* scores = (float*)d_ws;   // 64*10647*4 = 2.7 MB

    dim3 g1((NANCH + 255)/256, BATCH);
    score_kernel<<<g1, 256, 0, stream>>>(c13, p13, c26, p26, c52, p52, scores);
    nms_kernel<<<BATCH, THREADS, 0, stream>>>(scores, bbox13, bbox26, bbox52, out);
}

// Round 2
// 124.076 us; speedup vs baseline: 4.0961x; 4.0961x over previous
//
#include <hip/hip_runtime.h>

#define NUM_CLASSES 80
#define N13 507
#define N26 2028
#define N52 8112
#define NANCH (N13 + N26 + N52)   // 10647
#define BATCH 64
#define MAXB 100
#define NB 3720                    // float-bit buckets: (bits>>14) - 0xFC00, scores in (0.5, 79)
#define BOFF 0xFC00u

// ---------------- Phase 1: per-anchor score = p * (float)argmax(classes) ----------------
__global__ __launch_bounds__(256) void score_kernel(
    const float* __restrict__ c13, const float* __restrict__ p13,
    const float* __restrict__ c26, const float* __restrict__ p26,
    const float* __restrict__ c52, const float* __restrict__ p52,
    float* __restrict__ scores)
{
    int n = blockIdx.x * blockDim.x + threadIdx.x;
    int b = blockIdx.y;
    if (n >= NANCH) return;
    const float* cbase; const float* pbase;
    if (n < N13)            { cbase = c13 + ((size_t)b*N13 + n) * NUM_CLASSES;              pbase = p13 + (size_t)b*N13 + n; }
    else if (n < N13+N26)   { cbase = c26 + ((size_t)b*N26 + (n-N13)) * NUM_CLASSES;        pbase = p26 + (size_t)b*N26 + (n-N13); }
    else                    { cbase = c52 + ((size_t)b*N52 + (n-N13-N26)) * NUM_CLASSES;    pbase = p52 + (size_t)b*N52 + (n-N13-N26); }
    const float4* cp = (const float4*)cbase;
    float mx = -1.0f; int mi = 0;
    #pragma unroll
    for (int q = 0; q < NUM_CLASSES/4; ++q) {
        float4 v = cp[q];
        if (v.x > mx) { mx = v.x; mi = 4*q+0; }   // strict > keeps FIRST max (jnp.argmax)
        if (v.y > mx) { mx = v.y; mi = 4*q+1; }
        if (v.z > mx) { mx = v.z; mi = 4*q+2; }
        if (v.w > mx) { mx = v.w; mi = 4*q+3; }
    }
    scores[(size_t)b*NANCH + n] = pbase[0] * (float)mi;
}

__device__ __forceinline__ float4 load_box(const float* __restrict__ b13,
                                           const float* __restrict__ b26,
                                           const float* __restrict__ b52,
                                           int b, int n)
{
    if (n < N13)          return *(const float4*)(b13 + ((size_t)b*N13 + n)*4);
    else if (n < N13+N26) return *(const float4*)(b26 + ((size_t)b*N26 + (n-N13))*4);
    else                  return *(const float4*)(b52 + ((size_t)b*N52 + (n-N13-N26))*4);
}

// ---------------- Phase 2: counting-sort by score (desc) + sequential-scan NMS ----------------
// Equivalence to iterative argmax-NMS: greedy max selection == scan in (score desc, idx asc)
// order, accept iff IoU<=0.5 vs all previously accepted. Ties & arithmetic bit-match reference.
__global__ __launch_bounds__(1024) void nms_sort_scan(
    const float* __restrict__ scores,
    const float* __restrict__ b13, const float* __restrict__ b26, const float* __restrict__ b52,
    float* __restrict__ out)
{
    const int b   = blockIdx.x;
    const int tid = threadIdx.x;

    __shared__ unsigned long long lst[NANCH];   // 85.2 KB
    __shared__ unsigned int cnt[NB];            // 14.9 KB
    __shared__ unsigned int wsum[1024];         // 4 KB
    __shared__ float cb_y1[64], cb_x1[64], cb_y2[64], cb_x2[64], cb_ar[64];
    __shared__ float acc_y1[MAXB], acc_x1[MAXB], acc_y2[MAXB], acc_x2[MAXB], acc_ar[MAXB];
    __shared__ float outrec[MAXB][6];
    __shared__ int ncand_s, accN_s;

    const float* sc = scores + (size_t)b * NANCH;

    // ---- zero histogram ----
    for (int i = tid; i < NB; i += 1024) cnt[i] = 0u;
    __syncthreads();

    // ---- pass 1: count per bucket (monotone float-bit bucketing) ----
    for (int n = tid; n < NANCH; n += 1024) {
        float s = sc[n];
        if (s > 0.5f) {
            unsigned int bk = (__float_as_uint(s) >> 14) - BOFF;
            if (bk >= NB) bk = NB - 1;
            atomicAdd(&cnt[bk], 1u);
        }
    }
    __syncthreads();

    // ---- descending prefix (suffix-sum): start_desc[bk] = sum of counts of buckets > bk ----
    unsigned int loc[4]; unsigned int s4 = 0u;
    #pragma unroll
    for (int q = 0; q < 4; ++q) {
        int r = tid*4 + q;                       // reversed index: r=0 -> bucket NB-1 (highest score)
        unsigned int v = (r < NB) ? cnt[NB-1-r] : 0u;
        loc[q] = v; s4 += v;
    }
    wsum[tid] = s4;
    __syncthreads();
    for (int d = 1; d < 1024; d <<= 1) {         // Hillis-Steele inclusive scan
        unsigned int v = (tid >= d) ? wsum[tid-d] : 0u;
        __syncthreads();
        wsum[tid] += v;
        __syncthreads();
    }
    unsigned int run = wsum[tid] - s4;           // exclusive prefix
    if (tid == 0) ncand_s = (int)wsum[1023];     // total candidates
    #pragma unroll
    for (int q = 0; q < 4; ++q) {
        int r = tid*4 + q;
        if (r < NB) {
            int bk = NB-1-r;
            unsigned int c = loc[q];
            cnt[bk] = run;                       // overwrite count with start_desc
            run += c;
        }
    }
    __syncthreads();

    // ---- pass 2: scatter packed keys; key = (scorebits<<32) | ~idx  (desc => score desc, idx asc) ----
    for (int n = tid; n < NANCH; n += 1024) {
        float s = sc[n];
        if (s > 0.5f) {
            unsigned int bits = __float_as_uint(s);
            unsigned int bk = (bits >> 14) - BOFF;
            if (bk >= NB) bk = NB - 1;
            unsigned int pos = atomicAdd(&cnt[bk], 1u);
            lst[pos] = ((unsigned long long)bits << 32) | (unsigned long long)(0xFFFFFFFFu - (unsigned int)n);
        }
    }
    __syncthreads();
    // now cnt[bk] = end_desc[bk]; start_desc[bk] = cnt[bk+1] (or 0 for bk==NB-1)

    // ---- within-bucket insertion sort (tiny buckets; makes order exact & deterministic) ----
    for (int bk = tid; bk < NB; bk += 1024) {
        unsigned int e  = cnt[bk];
        unsigned int st = (bk+1 < NB) ? cnt[bk+1] : 0u;
        for (unsigned int i = st + 1; i < e; ++i) {
            unsigned long long key = lst[i];
            unsigned int j = i;
            while (j > st && lst[j-1] < key) { lst[j] = lst[j-1]; --j; }
            lst[j] = key;
        }
    }
    __syncthreads();

    // ---- wave 0: chunked sequential scan ----
    if (tid < 64) {
        const int lane = tid;
        const int ncand = ncand_s;
        int accN = 0;
        for (int c = 0; c < ncand && accN < MAXB; c += 64) {
            int m = ncand - c; if (m > 64) m = 64;
            bool act = lane < m;
            float s = 0.f, oy1=0.f, ox1=0.f, oy2=0.f, ox2=0.f;
            float y1=0.f, x1=0.f, y2=0.f, x2=0.f, ar=0.f;
            if (act) {
                unsigned long long key = lst[c + lane];
                unsigned int n = 0xFFFFFFFFu - (unsigned int)(key & 0xFFFFFFFFull);
                s = __uint_as_float((unsigned int)(key >> 32));
                float4 bb = load_box(b13, b26, b52, b, (int)n);
                oy1 = bb.x; ox1 = bb.y; oy2 = bb.z; ox2 = bb.w;
                y1 = fminf(bb.x, bb.z); y2 = fmaxf(bb.x, bb.z);
                x1 = fminf(bb.y, bb.w); x2 = fmaxf(bb.y, bb.w);
                ar = (y2-y1)*(x2-x1);
            }
            cb_y1[lane]=y1; cb_x1[lane]=x1; cb_y2[lane]=y2; cb_x2[lane]=x2; cb_ar[lane]=ar;
            __asm__ volatile("s_waitcnt lgkmcnt(0)" ::: "memory");

            // suppressed by any already-accepted box? (exact reference arithmetic)
            bool supp = false;
            for (int j = 0; j < accN; ++j) {
                float iy1=fmaxf(y1,acc_y1[j]), iy2=fminf(y2,acc_y2[j]);
                float ix1=fmaxf(x1,acc_x1[j]), ix2=fminf(x2,acc_x2[j]);
                float inter=fmaxf(iy2-iy1,0.f)*fmaxf(ix2-ix1,0.f);
                float un=(ar+acc_ar[j])-inter;
                if (un > 0.f && inter/un > 0.5f) { supp = true; break; }
            }

            // in-chunk pairwise suppressor mask: bit j set if chunk-candidate j suppresses me
            unsigned long long mysupp = 0ull;
            for (int j = 0; j < m; ++j) {
                float iy1=fmaxf(y1,cb_y1[j]), iy2=fminf(y2,cb_y2[j]);
                float ix1=fmaxf(x1,cb_x1[j]), ix2=fminf(x2,cb_x2[j]);
                float inter=fmaxf(iy2-iy1,0.f)*fmaxf(ix2-ix1,0.f);
                float un=(ar+cb_ar[j])-inter;
                if (un > 0.f && inter/un > 0.5f) mysupp |= (1ull << j);
            }

            unsigned long long B = __ballot(supp);
            unsigned long long valid_m = (m >= 64) ? ~0ull : ((1ull << m) - 1ull);
            unsigned long long rem = (~B) & valid_m;
            while (rem && accN < MAXB) {
                int j = __builtin_ctzll(rem);    // lowest position = next in sorted order
                if (lane == j) {                 // accept: record box + output row
                    acc_y1[accN]=y1; acc_x1[accN]=x1; acc_y2[accN]=y2; acc_x2[accN]=x2; acc_ar[accN]=ar;
                    outrec[accN][0]=fminf(fmaxf(oy1,0.f),1.f);
                    outrec[accN][1]=fminf(fmaxf(ox1,0.f),1.f);
                    outrec[accN][2]=fminf(fmaxf(oy2,0.f),1.f);
                    outrec[accN][3]=fminf(fmaxf(ox2,0.f),1.f);
                    outrec[accN][4]=s;
                    outrec[accN][5]=0.f;
                }
                accN++;
                unsigned long long sb = __ballot((mysupp >> j) & 1ull);  // lanes j suppresses
                rem &= ~sb;
                rem &= ~(1ull << j);
            }
            __asm__ volatile("s_waitcnt lgkmcnt(0)" ::: "memory");  // acc writes visible to next chunk
        }
        if (lane == 0) accN_s = accN;
    }
    __syncthreads();

    // ---- block-wide output write ----
    const int accN = accN_s;
    float* outp = out + (size_t)b * (MAXB*6);
    for (int i = tid; i < MAXB*6; i += 1024) {
        int t = i / 6;
        outp[i] = (t < accN) ? outrec[t][i % 6] : 0.f;
    }
    if (tid == 0) out[(size_t)BATCH*(MAXB*6) + b] = (float)accN;
}

extern "C" void kernel_launch(void* const* d_in, const int* in_sizes, int n_in,
                              void* d_out, int out_size, void* d_ws, size_t ws_size,
                              hipStream_t stream)
{
    const float* bbox13 = (const float*)d_in[0];
    const float* p13    = (const float*)d_in[1];
    const float* c13    = (const float*)d_in[2];
    const float* bbox26 = (const float*)d_in[3];
    const float* p26    = (const float*)d_in[4];
    const float* c26    = (const float*)d_in[5];
    const float* bbox52 = (const float*)d_in[6];
    const float* p52    = (const float*)d_in[7];
    const float* c52    = (const float*)d_in[8];
    float* out    = (float*)d_out;
    float* scores = (float*)d_ws;   // 64*10647*4 = 2.7 MB

    dim3 g1((NANCH + 255)/256, BATCH);
    score_kernel<<<g1, 256, 0, stream>>>(c13, p13, c26, p26, c52, p52, scores);
    nms_sort_scan<<<BATCH, 1024, 0, stream>>>(scores, bbox13, bbox26, bbox52, out);
}

// Round 3
// 118.608 us; speedup vs baseline: 4.2850x; 1.0461x over previous
//
#include <hip/hip_runtime.h>

#define NUM_CLASSES 80
#define N13 507
#define N26 2028
#define N52 8112
#define NANCH (N13 + N26 + N52)   // 10647
#define BATCH 64
#define MAXB 100
#define NB 3720                    // float-bit buckets: (bits>>14) - 0xFC00, scores in (0.5, 79)
#define BOFF 0xFC00u

// ---------------- Phase 1: per-anchor score = p * (float)argmax(classes) ----------------
__global__ __launch_bounds__(256) void score_kernel(
    const float* __restrict__ c13, const float* __restrict__ p13,
    const float* __restrict__ c26, const float* __restrict__ p26,
    const float* __restrict__ c52, const float* __restrict__ p52,
    float* __restrict__ scores)
{
    int n = blockIdx.x * blockDim.x + threadIdx.x;
    int b = blockIdx.y;
    if (n >= NANCH) return;
    const float* cbase; const float* pbase;
    if (n < N13)            { cbase = c13 + ((size_t)b*N13 + n) * NUM_CLASSES;              pbase = p13 + (size_t)b*N13 + n; }
    else if (n < N13+N26)   { cbase = c26 + ((size_t)b*N26 + (n-N13)) * NUM_CLASSES;        pbase = p26 + (size_t)b*N26 + (n-N13); }
    else                    { cbase = c52 + ((size_t)b*N52 + (n-N13-N26)) * NUM_CLASSES;    pbase = p52 + (size_t)b*N52 + (n-N13-N26); }
    const float4* cp = (const float4*)cbase;
    float mx = -1.0f; int mi = 0;
    #pragma unroll
    for (int q = 0; q < NUM_CLASSES/4; ++q) {
        float4 v = cp[q];
        if (v.x > mx) { mx = v.x; mi = 4*q+0; }   // strict > keeps FIRST max (jnp.argmax)
        if (v.y > mx) { mx = v.y; mi = 4*q+1; }
        if (v.z > mx) { mx = v.z; mi = 4*q+2; }
        if (v.w > mx) { mx = v.w; mi = 4*q+3; }
    }
    scores[(size_t)b*NANCH + n] = pbase[0] * (float)mi;
}

__device__ __forceinline__ float4 load_box(const float* __restrict__ b13,
                                           const float* __restrict__ b26,
                                           const float* __restrict__ b52,
                                           int b, int n)
{
    if (n < N13)          return *(const float4*)(b13 + ((size_t)b*N13 + n)*4);
    else if (n < N13+N26) return *(const float4*)(b26 + ((size_t)b*N26 + (n-N13))*4);
    else                  return *(const float4*)(b52 + ((size_t)b*N52 + (n-N13-N26))*4);
}

// ---------------- Phase 2: counting-sort by score (desc) + sequential-scan NMS ----------------
// greedy argmax-NMS == scan in (score desc, idx asc) order, accept iff IoU<=0.5 vs all accepted.
__global__ __launch_bounds__(1024) void nms_sort_scan(
    const float* __restrict__ scores,
    const float* __restrict__ b13, const float* __restrict__ b26, const float* __restrict__ b52,
    float* __restrict__ out)
{
    const int b    = blockIdx.x;
    const int tid  = threadIdx.x;
    const int lane = tid & 63;
    const int wid  = tid >> 6;

    __shared__ unsigned long long lst[NANCH];   // 85.2 KB
    __shared__ unsigned int cnt[NB];            // 14.9 KB
    __shared__ unsigned int wtot[16];
    __shared__ float outrec[MAXB][6];
    __shared__ int ncand_s, accN_s;

    const float* sc = scores + (size_t)b * NANCH;

    // ---- zero histogram ----
    for (int i = tid; i < NB; i += 1024) cnt[i] = 0u;
    __syncthreads();

    // ---- pass 1: count per bucket (monotone float-bit bucketing) ----
    for (int n = tid; n < NANCH; n += 1024) {
        float s = sc[n];
        if (s > 0.5f) {
            unsigned int bk = (__float_as_uint(s) >> 14) - BOFF;
            if (bk >= NB) bk = NB - 1;
            atomicAdd(&cnt[bk], 1u);
        }
    }
    __syncthreads();

    // ---- descending prefix via shfl wave-scan (start_desc[bk] = count of buckets > bk) ----
    unsigned int loc[4]; unsigned int s4 = 0u;
    #pragma unroll
    for (int q = 0; q < 4; ++q) {
        int r = tid*4 + q;                       // reversed: r=0 -> bucket NB-1 (highest score)
        unsigned int v = (r < NB) ? cnt[NB-1-r] : 0u;
        loc[q] = v; s4 += v;
    }
    unsigned int incl = s4;
    #pragma unroll
    for (int off = 1; off < 64; off <<= 1) {
        unsigned int v = __shfl_up(incl, off);
        if (lane >= off) incl += v;
    }
    if (lane == 63) wtot[wid] = incl;
    __syncthreads();
    unsigned int wexcl = 0u, total = 0u;
    #pragma unroll
    for (int w = 0; w < 16; ++w) { unsigned int t = wtot[w]; if (w < wid) wexcl += t; total += t; }
    unsigned int run = wexcl + (incl - s4);      // exclusive prefix over reversed buckets
    if (tid == 0) ncand_s = (int)total;
    __syncthreads();                             // cnt reads above done before overwrite
    #pragma unroll
    for (int q = 0; q < 4; ++q) {
        int r = tid*4 + q;
        if (r < NB) {
            int bk = NB-1-r;
            unsigned int c = loc[q];
            cnt[bk] = run;                       // overwrite count with start_desc
            run += c;
        }
    }
    __syncthreads();

    // ---- pass 2: scatter packed keys; key = (scorebits<<32) | ~idx (desc => score desc, idx asc) ----
    for (int n = tid; n < NANCH; n += 1024) {
        float s = sc[n];
        if (s > 0.5f) {
            unsigned int bits = __float_as_uint(s);
            unsigned int bk = (bits >> 14) - BOFF;
            if (bk >= NB) bk = NB - 1;
            unsigned int pos = atomicAdd(&cnt[bk], 1u);
            lst[pos] = ((unsigned long long)bits << 32) | (unsigned long long)(0xFFFFFFFFu - (unsigned int)n);
        }
    }
    __syncthreads();
    // cnt[bk] = end_desc[bk]; start_desc[bk] = cnt[bk+1] (or 0 for bk==NB-1)

    // ---- within-bucket insertion sort (exact (score desc, idx asc) order, deterministic) ----
    for (int bk = tid; bk < NB; bk += 1024) {
        unsigned int e  = cnt[bk];
        unsigned int st = (bk+1 < NB) ? cnt[bk+1] : 0u;
        for (unsigned int i = st + 1; i < e; ++i) {
            unsigned long long key = lst[i];
            unsigned int j = i;
            while (j > st && lst[j-1] < key) { lst[j] = lst[j-1]; --j; }
            lst[j] = key;
        }
    }
    __syncthreads();

    // ---- wave 0: chunked sequential scan; accepted boxes live in registers (shfl broadcast) ----
    if (wid == 0) {
        const int ncand = ncand_s;
        int accN = 0;
        // accepted slots: slot t in lane t (t<64, set A) or lane t-64 (set B)
        float aAy1=0.f, aAx1=0.f, aAy2=0.f, aAx2=0.f, aAar=0.f;
        float aBy1=0.f, aBx1=0.f, aBy2=0.f, aBx2=0.f, aBar=0.f;

        // software pipeline: preload chunk 0
        unsigned long long key = 0ull;
        float4 bb = make_float4(0.f,0.f,0.f,0.f);
        float s = 0.f;
        if (lane < ncand) {
            key = lst[lane];
            unsigned int n = 0xFFFFFFFFu - (unsigned int)(key & 0xFFFFFFFFull);
            s = __uint_as_float((unsigned int)(key >> 32));
            bb = load_box(b13, b26, b52, b, (int)n);
        }

        for (int c = 0; c < ncand && accN < MAXB; c += 64) {
            int m = ncand - c; if (m > 64) m = 64;
            // current chunk candidate (already loaded)
            float oy1 = bb.x, ox1 = bb.y, oy2 = bb.z, ox2 = bb.w, cs = s;
            float y1 = fminf(oy1, oy2), y2 = fmaxf(oy1, oy2);
            float x1 = fminf(ox1, ox2), x2 = fmaxf(ox1, ox2);
            float ar = (y2-y1)*(x2-x1);

            // prefetch next chunk (no barriers in this loop -> stays in flight)
            int nc = c + 64;
            if (nc + lane < ncand) {
                key = lst[nc + lane];
                unsigned int n = 0xFFFFFFFFu - (unsigned int)(key & 0xFFFFFFFFull);
                s = __uint_as_float((unsigned int)(key >> 32));
                bb = load_box(b13, b26, b52, b, (int)n);
            } else { s = 0.f; bb = make_float4(0.f,0.f,0.f,0.f); }

            // --- suppressed by any already-accepted box? (register slots + shfl broadcast) ---
            bool supp = (lane >= m);
            for (int j = 0; j < accN; ++j) {
                float jy1, jx1, jy2, jx2, jar;
                if (j < 64) {
                    jy1=__shfl(aAy1,j); jx1=__shfl(aAx1,j); jy2=__shfl(aAy2,j);
                    jx2=__shfl(aAx2,j); jar=__shfl(aAar,j);
                } else {
                    int jj = j-64;
                    jy1=__shfl(aBy1,jj); jx1=__shfl(aBx1,jj); jy2=__shfl(aBy2,jj);
                    jx2=__shfl(aBx2,jj); jar=__shfl(aBar,jj);
                }
                float iy1=fmaxf(y1,jy1), iy2=fminf(y2,jy2);
                float ix1=fmaxf(x1,jx1), ix2=fminf(x2,jx2);
                float inter=fmaxf(iy2-iy1,0.f)*fmaxf(ix2-ix1,0.f);
                float un=(ar+jar)-inter;                  // own area first, as in reference
                if (un > 0.f && inter/un > 0.5f) supp = true;
                if (__ballot(!supp) == 0ull) break;       // whole chunk dead, wave-uniform
            }

            // --- lazy resolve: accept lowest index, suppress on the fly ---
            unsigned long long valid_m = (m >= 64) ? ~0ull : ((1ull << m) - 1ull);
            unsigned long long rem = (~__ballot(supp)) & valid_m;
            while (rem && accN < MAXB) {
                int j = __builtin_ctzll(rem);             // next in sorted order
                float jy1=__shfl(y1,j), jx1=__shfl(x1,j), jy2=__shfl(y2,j);
                float jx2=__shfl(x2,j), jar=__shfl(ar,j);
                if (accN < 64) {
                    if (lane == accN)    { aAy1=jy1; aAx1=jx1; aAy2=jy2; aAx2=jx2; aAar=jar; }
                } else {
                    if (lane == accN-64) { aBy1=jy1; aBx1=jx1; aBy2=jy2; aBx2=jx2; aBar=jar; }
                }
                if (lane == j) {                          // accepting lane writes its own record
                    outrec[accN][0]=fminf(fmaxf(oy1,0.f),1.f);
                    outrec[accN][1]=fminf(fmaxf(ox1,0.f),1.f);
                    outrec[accN][2]=fminf(fmaxf(oy2,0.f),1.f);
                    outrec[accN][3]=fminf(fmaxf(ox2,0.f),1.f);
                    outrec[accN][4]=cs;
                    outrec[accN][5]=0.f;
                }
                float iy1=fmaxf(y1,jy1), iy2=fminf(y2,jy2);
                float ix1=fmaxf(x1,jx1), ix2=fminf(x2,jx2);
                float inter=fmaxf(iy2-iy1,0.f)*fmaxf(ix2-ix1,0.f);
                float un=(ar+jar)-inter;
                bool kill = (un > 0.f) && (inter/un > 0.5f);
                rem &= ~__ballot(kill);
                rem &= ~(1ull << j);
                accN++;
            }
        }
        if (lane == 0) accN_s = accN;
    }
    __syncthreads();

    // ---- block-wide output write ----
    const int accN = accN_s;
    float* outp = out + (size_t)b * (MAXB*6);
    for (int i = tid; i < MAXB*6; i += 1024) {
        int t = i / 6;
        outp[i] = (t < accN) ? outrec[t][i % 6] : 0.f;
    }
    if (tid == 0) out[(size_t)BATCH*(MAXB*6) + b] = (float)accN;
}

extern "C" void kernel_launch(void* const* d_in, const int* in_sizes, int n_in,
                              void* d_out, int out_size, void* d_ws, size_t ws_size,
                              hipStream_t stream)
{
    const float* bbox13 = (const float*)d_in[0];
    const float* p13    = (const float*)d_in[1];
    const float* c13    = (const float*)d_in[2];
    const float* bbox26 = (const float*)d_in[3];
    const float* p26    = (const float*)d_in[4];
    const float* c26    = (const float*)d_in[5];
    const float* bbox52 = (const float*)d_in[6];
    const float* p52    = (const float*)d_in[7];
    const float* c52    = (const float*)d_in[8];
    float* out    = (float*)d_out;
    float* scores = (float*)d_ws;   // 64*10647*4 = 2.7 MB

    dim3 g1((NANCH + 255)/256, BATCH);
    score_kernel<<<g1, 256, 0, stream>>>(c13, p13, c26, p26, c52, p52, scores);
    nms_sort_scan<<<BATCH, 1024, 0, stream>>>(scores, bbox13, bbox26, bbox52, out);
}

// Round 4
// 97.850 us; speedup vs baseline: 5.1940x; 1.2121x over previous
//
#include <hip/hip_runtime.h>

#define NUM_CLASSES 80
#define N13 507
#define N26 2028
#define N52 8112
#define NANCH (N13 + N26 + N52)   // 10647
#define BATCH 64
#define MAXB 100
#define NB 3720                    // float-bit buckets: (bits>>14) - 0xFC00, scores in (0.5, 79)
#define BOFF 0xFC00u

// ---------------- Phase 1: per-anchor score = p * (float)argmax(classes) ----------------
__global__ __launch_bounds__(256) void score_kernel(
    const float* __restrict__ c13, const float* __restrict__ p13,
    const float* __restrict__ c26, const float* __restrict__ p26,
    const float* __restrict__ c52, const float* __restrict__ p52,
    float* __restrict__ scores)
{
    int n = blockIdx.x * blockDim.x + threadIdx.x;
    int b = blockIdx.y;
    if (n >= NANCH) return;
    const float* cbase; const float* pbase;
    if (n < N13)            { cbase = c13 + ((size_t)b*N13 + n) * NUM_CLASSES;              pbase = p13 + (size_t)b*N13 + n; }
    else if (n < N13+N26)   { cbase = c26 + ((size_t)b*N26 + (n-N13)) * NUM_CLASSES;        pbase = p26 + (size_t)b*N26 + (n-N13); }
    else                    { cbase = c52 + ((size_t)b*N52 + (n-N13-N26)) * NUM_CLASSES;    pbase = p52 + (size_t)b*N52 + (n-N13-N26); }
    const float4* cp = (const float4*)cbase;
    float mx = -1.0f; int mi = 0;
    #pragma unroll
    for (int q = 0; q < NUM_CLASSES/4; ++q) {
        float4 v = cp[q];
        if (v.x > mx) { mx = v.x; mi = 4*q+0; }   // strict > keeps FIRST max (jnp.argmax)
        if (v.y > mx) { mx = v.y; mi = 4*q+1; }
        if (v.z > mx) { mx = v.z; mi = 4*q+2; }
        if (v.w > mx) { mx = v.w; mi = 4*q+3; }
    }
    scores[(size_t)b*NANCH + n] = pbase[0] * (float)mi;
}

__device__ __forceinline__ float4 load_box(const float* __restrict__ b13,
                                           const float* __restrict__ b26,
                                           const float* __restrict__ b52,
                                           int b, int n)
{
    if (n < N13)          return *(const float4*)(b13 + ((size_t)b*N13 + n)*4);
    else if (n < N13+N26) return *(const float4*)(b26 + ((size_t)b*N26 + (n-N13))*4);
    else                  return *(const float4*)(b52 + ((size_t)b*N52 + (n-N13-N26))*4);
}

// ---------------- Phase 2: counting-sort by score (desc) + wave-parallel scan NMS ----------------
// greedy argmax-NMS == scan in (score desc, idx asc) order, accept iff IoU<=0.5 vs all accepted.
// All 16 waves hold the SAME 64-candidate chunk; wave w checks accepted slice j = w, w+16, ...
__global__ __launch_bounds__(1024) void nms_sort_scan(
    const float* __restrict__ scores,
    const float* __restrict__ b13, const float* __restrict__ b26, const float* __restrict__ b52,
    float* __restrict__ out)
{
    const int b    = blockIdx.x;
    const int tid  = threadIdx.x;
    const int lane = tid & 63;
    const int wid  = tid >> 6;

    __shared__ unsigned long long lst[NANCH];   // 85.2 KB
    __shared__ unsigned int cnt[NB];            // 14.9 KB
    __shared__ unsigned int wtot[16];
    __shared__ float4 acc4[MAXB];               // accepted canonical boxes (y1,x1,y2,x2)
    __shared__ unsigned long long sup_lds[16];
    __shared__ float outrec[MAXB][6];
    __shared__ int ncand_s, accN_s;

    const float* sc = scores + (size_t)b * NANCH;

    // ---- zero histogram ----
    for (int i = tid; i < NB; i += 1024) cnt[i] = 0u;
    if (tid == 0) accN_s = 0;
    __syncthreads();

    // ---- pass 1: count per bucket (monotone float-bit bucketing) ----
    for (int n = tid; n < NANCH; n += 1024) {
        float s = sc[n];
        if (s > 0.5f) {
            unsigned int bk = (__float_as_uint(s) >> 14) - BOFF;
            if (bk >= NB) bk = NB - 1;
            atomicAdd(&cnt[bk], 1u);
        }
    }
    __syncthreads();

    // ---- descending prefix via shfl wave-scan (start_desc[bk] = count of buckets > bk) ----
    unsigned int loc[4]; unsigned int s4 = 0u;
    #pragma unroll
    for (int q = 0; q < 4; ++q) {
        int r = tid*4 + q;                       // reversed: r=0 -> bucket NB-1 (highest score)
        unsigned int v = (r < NB) ? cnt[NB-1-r] : 0u;
        loc[q] = v; s4 += v;
    }
    unsigned int incl = s4;
    #pragma unroll
    for (int off = 1; off < 64; off <<= 1) {
        unsigned int v = __shfl_up(incl, off);
        if (lane >= off) incl += v;
    }
    if (lane == 63) wtot[wid] = incl;
    __syncthreads();
    unsigned int wexcl = 0u, total = 0u;
    #pragma unroll
    for (int w = 0; w < 16; ++w) { unsigned int t = wtot[w]; if (w < wid) wexcl += t; total += t; }
    unsigned int run = wexcl + (incl - s4);      // exclusive prefix over reversed buckets
    if (tid == 0) ncand_s = (int)total;
    __syncthreads();                             // cnt reads above done before overwrite
    #pragma unroll
    for (int q = 0; q < 4; ++q) {
        int r = tid*4 + q;
        if (r < NB) {
            int bk = NB-1-r;
            unsigned int c = loc[q];
            cnt[bk] = run;                       // overwrite count with start_desc
            run += c;
        }
    }
    __syncthreads();

    // ---- pass 2: scatter packed keys; key = (scorebits<<32) | ~idx (desc => score desc, idx asc) ----
    for (int n = tid; n < NANCH; n += 1024) {
        float s = sc[n];
        if (s > 0.5f) {
            unsigned int bits = __float_as_uint(s);
            unsigned int bk = (bits >> 14) - BOFF;
            if (bk >= NB) bk = NB - 1;
            unsigned int pos = atomicAdd(&cnt[bk], 1u);
            lst[pos] = ((unsigned long long)bits << 32) | (unsigned long long)(0xFFFFFFFFu - (unsigned int)n);
        }
    }
    __syncthreads();
    // cnt[bk] = end_desc[bk]; start_desc[bk] = cnt[bk+1] (or 0 for bk==NB-1)

    // ---- within-bucket insertion sort (exact (score desc, idx asc) order, deterministic) ----
    for (int bk = tid; bk < NB; bk += 1024) {
        unsigned int e  = cnt[bk];
        unsigned int st = (bk+1 < NB) ? cnt[bk+1] : 0u;
        for (unsigned int i = st + 1; i < e; ++i) {
            unsigned long long key = lst[i];
            unsigned int j = i;
            while (j > st && lst[j-1] < key) { lst[j] = lst[j-1]; --j; }
            lst[j] = key;
        }
    }
    __syncthreads();

    // ---- wave-parallel chunked scan ----
    const int ncand = ncand_s;
    int accN = 0;

    // prefetch chunk 0 (every wave keeps its own copy of the SAME chunk)
    unsigned long long key = 0ull;
    float4 bb = make_float4(0.f,0.f,0.f,0.f);
    float s = 0.f;
    if (lane < ncand) {
        key = lst[lane];
        unsigned int n = 0xFFFFFFFFu - (unsigned int)(key & 0xFFFFFFFFull);
        s = __uint_as_float((unsigned int)(key >> 32));
        bb = load_box(b13, b26, b52, b, (int)n);
    }

    for (int c = 0; c < ncand; c += 64) {
        if (accN >= MAXB) break;                 // accN block-uniform here
        int m = ncand - c; if (m > 64) m = 64;
        float oy1 = bb.x, ox1 = bb.y, oy2 = bb.z, ox2 = bb.w, cs = s;
        float y1 = fminf(oy1, oy2), y2 = fmaxf(oy1, oy2);
        float x1 = fminf(ox1, ox2), x2 = fmaxf(ox1, ox2);
        float ar = (y2-y1)*(x2-x1);

        // prefetch next chunk
        int nc = c + 64;
        if (nc + lane < ncand) {
            key = lst[nc + lane];
            unsigned int n = 0xFFFFFFFFu - (unsigned int)(key & 0xFFFFFFFFull);
            s = __uint_as_float((unsigned int)(key >> 32));
            bb = load_box(b13, b26, b52, b, (int)n);
        } else { s = 0.f; bb = make_float4(0.f,0.f,0.f,0.f); }

        // --- wave w checks accepted slice {w, w+16, ...}; no break -> ds_reads pipeline ---
        bool supp = (lane >= m);
        #pragma unroll 2
        for (int j = wid; j < accN; j += 16) {
            float4 aj = acc4[j];                 // broadcast read, conflict-free
            float jar = (aj.z - aj.x) * (aj.w - aj.y);   // bit-identical to ref's area
            float iy1=fmaxf(y1,aj.x), iy2=fminf(y2,aj.z);
            float ix1=fmaxf(x1,aj.y), ix2=fminf(x2,aj.w);
            float inter=fmaxf(iy2-iy1,0.f)*fmaxf(ix2-ix1,0.f);
            float un=(ar+jar)-inter;
            supp |= (un > 0.f) && (inter/un > 0.5f);
        }
        unsigned long long bal = __ballot(supp);
        if (lane == 0) sup_lds[wid] = bal;
        __syncthreads();

        // --- wave 0: lazy in-order resolve on the OR of all partial ballots ---
        if (wid == 0) {
            unsigned long long B = 0ull;
            #pragma unroll
            for (int w = 0; w < 16; ++w) B |= sup_lds[w];
            unsigned long long valid_m = (m >= 64) ? ~0ull : ((1ull << m) - 1ull);
            unsigned long long rem = (~B) & valid_m;
            while (rem && accN < MAXB) {
                int j = __builtin_ctzll(rem);    // next in sorted order
                float jy1=__shfl(y1,j), jx1=__shfl(x1,j), jy2=__shfl(y2,j);
                float jx2=__shfl(x2,j), jar=__shfl(ar,j);
                if (lane == j) {                 // accepting lane appends its own record
                    acc4[accN] = make_float4(y1, x1, y2, x2);
                    outrec[accN][0]=fminf(fmaxf(oy1,0.f),1.f);
                    outrec[accN][1]=fminf(fmaxf(ox1,0.f),1.f);
                    outrec[accN][2]=fminf(fmaxf(oy2,0.f),1.f);
                    outrec[accN][3]=fminf(fmaxf(ox2,0.f),1.f);
                    outrec[accN][4]=cs;
                    outrec[accN][5]=0.f;
                }
                float iy1=fmaxf(y1,jy1), iy2=fminf(y2,jy2);
                float ix1=fmaxf(x1,jx1), ix2=fminf(x2,jx2);
                float inter=fmaxf(iy2-iy1,0.f)*fmaxf(ix2-ix1,0.f);
                float un=(ar+jar)-inter;
                bool kill = (un > 0.f) && (inter/un > 0.5f);
                rem &= ~__ballot(kill);
                rem &= ~(1ull << j);
                accN++;
            }
            if (lane == 0) accN_s = accN;
        }
        __syncthreads();
        accN = accN_s;
    }

    // ---- block-wide output write ----
    const int accNf = accN_s;
    float* outp = out + (size_t)b * (MAXB*6);
    for (int i = tid; i < MAXB*6; i += 1024) {
        int t = i / 6;
        outp[i] = (t < accNf) ? outrec[t][i % 6] : 0.f;
    }
    if (tid == 0) out[(size_t)BATCH*(MAXB*6) + b] = (float)accNf;
}

extern "C" void kernel_launch(void* const* d_in, const int* in_sizes, int n_in,
                              void* d_out, int out_size, void* d_ws, size_t ws_size,
                              hipStream_t stream)
{
    const float* bbox13 = (const float*)d_in[0];
    const float* p13    = (const float*)d_in[1];
    const float* c13    = (const float*)d_in[2];
    const float* bbox26 = (const float*)d_in[3];
    const float* p26    = (const float*)d_in[4];
    const float* c26    = (const float*)d_in[5];
    const float* bbox52 = (const float*)d_in[6];
    const float* p52    = (const float*)d_in[7];
    const float* c52    = (const float*)d_in[8];
    float* out    = (float*)d_out;
    float* scores = (float*)d_ws;   // 64*10647*4 = 2.7 MB

    dim3 g1((NANCH + 255)/256, BATCH);
    score_kernel<<<g1, 256, 0, stream>>>(c13, p13, c26, p26, c52, p52, scores);
    nms_sort_scan<<<BATCH, 1024, 0, stream>>>(scores, bbox13, bbox26, bbox52, out);
}

// Round 5
// 84.109 us; speedup vs baseline: 6.0425x; 1.1634x over previous
//
#include <hip/hip_runtime.h>

#define NUM_CLASSES 80
#define N13 507
#define N26 2028
#define N52 8112
#define NANCH (N13 + N26 + N52)   // 10647
#define BATCH 64
#define MAXB 100
#define NB 3720                    // float-bit buckets: (bits>>14) - 0xFC00, scores in (0.5, 79)
#define BOFF 0xFC00u
#define KPT 11                     // ceil(NANCH/1024)

// ---------------- Phase 1: per-anchor score = p * (float)argmax(classes) ----------------
__global__ __launch_bounds__(256) void score_kernel(
    const float* __restrict__ c13, const float* __restrict__ p13,
    const float* __restrict__ c26, const float* __restrict__ p26,
    const float* __restrict__ c52, const float* __restrict__ p52,
    float* __restrict__ scores)
{
    int n = blockIdx.x * blockDim.x + threadIdx.x;
    int b = blockIdx.y;
    if (n >= NANCH) return;
    const float* cbase; const float* pbase;
    if (n < N13)            { cbase = c13 + ((size_t)b*N13 + n) * NUM_CLASSES;              pbase = p13 + (size_t)b*N13 + n; }
    else if (n < N13+N26)   { cbase = c26 + ((size_t)b*N26 + (n-N13)) * NUM_CLASSES;        pbase = p26 + (size_t)b*N26 + (n-N13); }
    else                    { cbase = c52 + ((size_t)b*N52 + (n-N13-N26)) * NUM_CLASSES;    pbase = p52 + (size_t)b*N52 + (n-N13-N26); }
    const float4* cp = (const float4*)cbase;
    float mx = -1.0f; int mi = 0;
    #pragma unroll
    for (int q = 0; q < NUM_CLASSES/4; ++q) {
        float4 v = cp[q];
        if (v.x > mx) { mx = v.x; mi = 4*q+0; }   // strict > keeps FIRST max (jnp.argmax)
        if (v.y > mx) { mx = v.y; mi = 4*q+1; }
        if (v.z > mx) { mx = v.z; mi = 4*q+2; }
        if (v.w > mx) { mx = v.w; mi = 4*q+3; }
    }
    scores[(size_t)b*NANCH + n] = pbase[0] * (float)mi;
}

__device__ __forceinline__ float4 load_box(const float* __restrict__ b13,
                                           const float* __restrict__ b26,
                                           const float* __restrict__ b52,
                                           int b, int n)
{
    if (n < N13)          return *(const float4*)(b13 + ((size_t)b*N13 + n)*4);
    else if (n < N13+N26) return *(const float4*)(b26 + ((size_t)b*N26 + (n-N13))*4);
    else                  return *(const float4*)(b52 + ((size_t)b*N52 + (n-N13-N26))*4);
}

// ---------------- Phase 2: counting-sort by score (desc) + wave-parallel scan NMS ----------------
// greedy argmax-NMS == scan in (score desc, idx asc) order, accept iff IoU<=0.5 vs all accepted.
__global__ __launch_bounds__(1024) void nms_sort_scan(
    const float* __restrict__ scores,
    const float* __restrict__ b13, const float* __restrict__ b26, const float* __restrict__ b52,
    float* __restrict__ out)
{
    const int b    = blockIdx.x;
    const int tid  = threadIdx.x;
    const int lane = tid & 63;
    const int wid  = tid >> 6;

    __shared__ unsigned long long lst[NANCH];   // 85.2 KB
    __shared__ unsigned int cnt[NB];            // 14.9 KB
    __shared__ unsigned int wtot[16];
    __shared__ float4 acc4[MAXB];               // accepted canonical boxes (y1,x1,y2,x2)
    __shared__ unsigned long long sup_lds[16];
    __shared__ float outrec[MAXB][6];
    __shared__ int ncand_s, accN_s;

    const float* sc = scores + (size_t)b * NANCH;

    // ---- zero histogram ----
    for (int i = tid; i < NB; i += 1024) cnt[i] = 0u;
    if (tid == 0) accN_s = 0;
    __syncthreads();

    // ---- pass 1: count per bucket (monotone float-bit bucketing) ----
    for (int n = tid; n < NANCH; n += 1024) {
        float s = sc[n];
        if (s > 0.5f) {
            unsigned int bk = (__float_as_uint(s) >> 14) - BOFF;
            if (bk >= NB) bk = NB - 1;
            atomicAdd(&cnt[bk], 1u);
        }
    }
    __syncthreads();

    // ---- descending prefix via shfl wave-scan (start_desc[bk] = count of buckets > bk) ----
    unsigned int loc[4]; unsigned int s4 = 0u;
    #pragma unroll
    for (int q = 0; q < 4; ++q) {
        int r = tid*4 + q;                       // reversed: r=0 -> bucket NB-1 (highest score)
        unsigned int v = (r < NB) ? cnt[NB-1-r] : 0u;
        loc[q] = v; s4 += v;
    }
    unsigned int incl = s4;
    #pragma unroll
    for (int off = 1; off < 64; off <<= 1) {
        unsigned int v = __shfl_up(incl, off);
        if (lane >= off) incl += v;
    }
    if (lane == 63) wtot[wid] = incl;
    __syncthreads();
    unsigned int wexcl = 0u, total = 0u;
    #pragma unroll
    for (int w = 0; w < 16; ++w) { unsigned int t = wtot[w]; if (w < wid) wexcl += t; total += t; }
    unsigned int run = wexcl + (incl - s4);      // exclusive prefix over reversed buckets
    if (tid == 0) ncand_s = (int)total;
    __syncthreads();                             // cnt reads above done before overwrite
    #pragma unroll
    for (int q = 0; q < 4; ++q) {
        int r = tid*4 + q;
        if (r < NB) {
            int bk = NB-1-r;
            unsigned int c = loc[q];
            cnt[bk] = run;                       // overwrite count with start_desc
            run += c;
        }
    }
    __syncthreads();

    // ---- pass 2: scatter packed keys; key = (scorebits<<32) | ~idx (desc => score desc, idx asc) ----
    for (int n = tid; n < NANCH; n += 1024) {
        float s = sc[n];
        if (s > 0.5f) {
            unsigned int bits = __float_as_uint(s);
            unsigned int bk = (bits >> 14) - BOFF;
            if (bk >= NB) bk = NB - 1;
            unsigned int pos = atomicAdd(&cnt[bk], 1u);
            lst[pos] = ((unsigned long long)bits << 32) | (unsigned long long)(0xFFFFFFFFu - (unsigned int)n);
        }
    }
    __syncthreads();
    // cnt[bk] = end_desc[bk]; start_desc[bk] = cnt[bk+1] (or 0 for bk==NB-1)

    // ---- parallel rank-and-permute within buckets (replaces divergent insertion sort) ----
    // All keys distinct -> final slot of key at pos p: start(bk) + #{bucket-mates with larger key}.
    const int ncand = ncand_s;
    unsigned long long myk[KPT]; int mytgt[KPT];
    #pragma unroll
    for (int k = 0; k < KPT; ++k) {
        int p = tid + (k << 10);
        mytgt[k] = -1;
        if (p < ncand) {
            unsigned long long key = lst[p];
            unsigned int bk = (unsigned int)(key >> 46) - BOFF;   // (bits>>14): score bits are key>>32
            if (bk >= NB) bk = NB - 1;
            unsigned int st = (bk+1 < NB) ? cnt[bk+1] : 0u;
            unsigned int e  = cnt[bk];
            unsigned int rank = 0u;
            for (unsigned int q = st; q < e; ++q) {
                unsigned long long other = lst[q];
                rank += (other > key) ? 1u : 0u;
            }
            myk[k] = key; mytgt[k] = (int)(st + rank);
        }
    }
    __syncthreads();
    #pragma unroll
    for (int k = 0; k < KPT; ++k) {
        if (mytgt[k] >= 0) lst[mytgt[k]] = myk[k];
    }
    __syncthreads();

    // ---- wave-parallel chunked scan ----
    int accN = 0;

    // prefetch chunk 0 (every wave keeps its own copy of the SAME chunk)
    unsigned long long key = 0ull;
    float4 bb = make_float4(0.f,0.f,0.f,0.f);
    float s = 0.f;
    if (lane < ncand) {
        key = lst[lane];
        unsigned int n = 0xFFFFFFFFu - (unsigned int)(key & 0xFFFFFFFFull);
        s = __uint_as_float((unsigned int)(key >> 32));
        bb = load_box(b13, b26, b52, b, (int)n);
    }

    for (int c = 0; c < ncand; c += 64) {
        if (accN >= MAXB) break;                 // accN block-uniform here
        int m = ncand - c; if (m > 64) m = 64;
        float oy1 = bb.x, ox1 = bb.y, oy2 = bb.z, ox2 = bb.w, cs = s;
        float y1 = fminf(oy1, oy2), y2 = fmaxf(oy1, oy2);
        float x1 = fminf(ox1, ox2), x2 = fmaxf(ox1, ox2);
        float ar = (y2-y1)*(x2-x1);

        // prefetch next chunk
        int nc = c + 64;
        if (nc + lane < ncand) {
            key = lst[nc + lane];
            unsigned int n = 0xFFFFFFFFu - (unsigned int)(key & 0xFFFFFFFFull);
            s = __uint_as_float((unsigned int)(key >> 32));
            bb = load_box(b13, b26, b52, b, (int)n);
        } else { s = 0.f; bb = make_float4(0.f,0.f,0.f,0.f); }

        // --- wave w checks accepted slice {w, w+16, ...}; no break -> ds_reads pipeline ---
        bool supp = (lane >= m);
        #pragma unroll 2
        for (int j = wid; j < accN; j += 16) {
            float4 aj = acc4[j];                 // broadcast read, conflict-free
            float jar = (aj.z - aj.x) * (aj.w - aj.y);   // bit-identical to ref's area
            float iy1=fmaxf(y1,aj.x), iy2=fminf(y2,aj.z);
            float ix1=fmaxf(x1,aj.y), ix2=fminf(x2,aj.w);
            float inter=fmaxf(iy2-iy1,0.f)*fmaxf(ix2-ix1,0.f);
            float un=(ar+jar)-inter;
            supp |= (un > 0.f) && (inter/un > 0.5f);
        }
        unsigned long long bal = __ballot(supp);
        if (lane == 0) sup_lds[wid] = bal;
        __syncthreads();

        // --- wave 0: lazy in-order resolve on the OR of all partial ballots ---
        if (wid == 0) {
            unsigned long long B = 0ull;
            #pragma unroll
            for (int w = 0; w < 16; ++w) B |= sup_lds[w];
            unsigned long long valid_m = (m >= 64) ? ~0ull : ((1ull << m) - 1ull);
            unsigned long long rem = (~B) & valid_m;
            while (rem && accN < MAXB) {
                int j = __builtin_ctzll(rem);    // next in sorted order
                float jy1=__shfl(y1,j), jx1=__shfl(x1,j), jy2=__shfl(y2,j);
                float jx2=__shfl(x2,j), jar=__shfl(ar,j);
                if (lane == j) {                 // accepting lane appends its own record
                    acc4[accN] = make_float4(y1, x1, y2, x2);
                    outrec[accN][0]=fminf(fmaxf(oy1,0.f),1.f);
                    outrec[accN][1]=fminf(fmaxf(ox1,0.f),1.f);
                    outrec[accN][2]=fminf(fmaxf(oy2,0.f),1.f);
                    outrec[accN][3]=fminf(fmaxf(ox2,0.f),1.f);
                    outrec[accN][4]=cs;
                    outrec[accN][5]=0.f;
                }
                float iy1=fmaxf(y1,jy1), iy2=fminf(y2,jy2);
                float ix1=fmaxf(x1,jx1), ix2=fminf(x2,jx2);
                float inter=fmaxf(iy2-iy1,0.f)*fmaxf(ix2-ix1,0.f);
                float un=(ar+jar)-inter;
                bool kill = (un > 0.f) && (inter/un > 0.5f);
                rem &= ~__ballot(kill);
                rem &= ~(1ull << j);
                accN++;
            }
            if (lane == 0) accN_s = accN;
        }
        __syncthreads();
        accN = accN_s;
    }

    // ---- block-wide output write ----
    const int accNf = accN_s;
    float* outp = out + (size_t)b * (MAXB*6);
    for (int i = tid; i < MAXB*6; i += 1024) {
        int t = i / 6;
        outp[i] = (t < accNf) ? outrec[t][i % 6] : 0.f;
    }
    if (tid == 0) out[(size_t)BATCH*(MAXB*6) + b] = (float)accNf;
}

extern "C" void kernel_launch(void* const* d_in, const int* in_sizes, int n_in,
                              void* d_out, int out_size, void* d_ws, size_t ws_size,
                              hipStream_t stream)
{
    const float* bbox13 = (const float*)d_in[0];
    const float* p13    = (const float*)d_in[1];
    const float* c13    = (const float*)d_in[2];
    const float* bbox26 = (const float*)d_in[3];
    const float* p26    = (const float*)d_in[4];
    const float* c26    = (const float*)d_in[5];
    const float* bbox52 = (const float*)d_in[6];
    const float* p52    = (const float*)d_in[7];
    const float* c52    = (const float*)d_in[8];
    float* out    = (float*)d_out;
    float* scores = (float*)d_ws;   // 64*10647*4 = 2.7 MB

    dim3 g1((NANCH + 255)/256, BATCH);
    score_kernel<<<g1, 256, 0, stream>>>(c13, p13, c26, p26, c52, p52, scores);
    nms_sort_scan<<<BATCH, 1024, 0, stream>>>(scores, bbox13, bbox26, bbox52, out);
}

// Round 6
// 75.619 us; speedup vs baseline: 6.7210x; 1.1123x over previous
//
#include <hip/hip_runtime.h>

#define NUM_CLASSES 80
#define N13 507
#define N26 2028
#define N52 8112
#define NANCH (N13 + N26 + N52)   // 10647
#define BATCH 64
#define MAXB 100
#define NB 3720                    // float-bit buckets: (bits>>14) - 0xFC00, scores in (0.5, 79)
#define BOFF 0xFC00u
#define KPT 11                     // ceil(NANCH/1024)
#define TOPK 1024                  // region target size (scan needs ~456 for 100 accepts)
#define LCAP 4096                  // LDS ring capacity (power of 2)
#define LMASK (LCAP-1)

typedef unsigned long long u64;

// ---------------- Phase 1: per-anchor score = p * (float)argmax(classes) ----------------
__global__ __launch_bounds__(256) void score_kernel(
    const float* __restrict__ c13, const float* __restrict__ p13,
    const float* __restrict__ c26, const float* __restrict__ p26,
    const float* __restrict__ c52, const float* __restrict__ p52,
    float* __restrict__ scores)
{
    int n = blockIdx.x * blockDim.x + threadIdx.x;
    int b = blockIdx.y;
    if (n >= NANCH) return;
    const float* cbase; const float* pbase;
    if (n < N13)            { cbase = c13 + ((size_t)b*N13 + n) * NUM_CLASSES;              pbase = p13 + (size_t)b*N13 + n; }
    else if (n < N13+N26)   { cbase = c26 + ((size_t)b*N26 + (n-N13)) * NUM_CLASSES;        pbase = p26 + (size_t)b*N26 + (n-N13); }
    else                    { cbase = c52 + ((size_t)b*N52 + (n-N13-N26)) * NUM_CLASSES;    pbase = p52 + (size_t)b*N52 + (n-N13-N26); }
    const float4* cp = (const float4*)cbase;
    float mx = -1.0f; int mi = 0;
    #pragma unroll
    for (int q = 0; q < NUM_CLASSES/4; ++q) {
        float4 v = cp[q];
        if (v.x > mx) { mx = v.x; mi = 4*q+0; }   // strict > keeps FIRST max (jnp.argmax)
        if (v.y > mx) { mx = v.y; mi = 4*q+1; }
        if (v.z > mx) { mx = v.z; mi = 4*q+2; }
        if (v.w > mx) { mx = v.w; mi = 4*q+3; }
    }
    scores[(size_t)b*NANCH + n] = pbase[0] * (float)mi;
}

__device__ __forceinline__ float4 load_box(const float* __restrict__ b13,
                                           const float* __restrict__ b26,
                                           const float* __restrict__ b52,
                                           int b, int n)
{
    if (n < N13)          return *(const float4*)(b13 + ((size_t)b*N13 + n)*4);
    else if (n < N13+N26) return *(const float4*)(b26 + ((size_t)b*N26 + (n-N13))*4);
    else                  return *(const float4*)(b52 + ((size_t)b*N52 + (n-N13-N26))*4);
}

// ---------------- Phase 2: top-K counting-sort by score (desc) + wave-parallel scan NMS -------
// greedy argmax-NMS == scan in (score desc, idx asc) order, accept iff IoU<=0.5 vs all accepted.
__global__ __launch_bounds__(1024) void nms_sort_scan(
    const float* __restrict__ scores,
    const float* __restrict__ b13, const float* __restrict__ b26, const float* __restrict__ b52,
    float* __restrict__ out)
{
    const int b    = blockIdx.x;
    const int tid  = threadIdx.x;
    const int lane = tid & 63;
    const int wid  = tid >> 6;

    __shared__ u64 lst[LCAP];                   // 32 KB ring of sorted candidates
    __shared__ unsigned int cnt[NB];            // 14.9 KB
    __shared__ unsigned int wtot[16];
    __shared__ float4 acc4[MAXB];               // accepted canonical boxes (y1,x1,y2,x2)
    __shared__ u64 sup_lds[16];
    __shared__ float outrec[MAXB][6];
    __shared__ int accN_s, T_s, L_s;

    const float* sc = scores + (size_t)b * NANCH;

    // ---- hoist all score loads (independent, land under the LDS zeroing) ----
    float sreg[KPT];
    #pragma unroll
    for (int k = 0; k < KPT; ++k) {
        int n = tid + (k << 10);
        sreg[k] = (n < NANCH) ? sc[n] : 0.f;
    }

    for (int i = tid; i < NB; i += 1024) cnt[i] = 0u;
    if (tid == 0) accN_s = 0;
    __syncthreads();

    // ---- histogram from registers ----
    #pragma unroll
    for (int k = 0; k < KPT; ++k) {
        float s = sreg[k];
        if (s > 0.5f) {
            unsigned int bk = (__float_as_uint(s) >> 14) - BOFF;
            if (bk >= NB) bk = NB - 1;
            atomicAdd(&cnt[bk], 1u);
        }
    }
    __syncthreads();

    // ---- descending prefix (start_desc) via shfl wave-scan + crossing-bucket finder ----
    unsigned int loc[4]; unsigned int s4 = 0u;
    #pragma unroll
    for (int q = 0; q < 4; ++q) {
        int r = tid*4 + q;                       // reversed: r=0 -> bucket NB-1 (highest score)
        unsigned int v = (r < NB) ? cnt[NB-1-r] : 0u;
        loc[q] = v; s4 += v;
    }
    unsigned int incl = s4;
    #pragma unroll
    for (int off = 1; off < 64; off <<= 1) {
        unsigned int v = __shfl_up(incl, off);
        if (lane >= off) incl += v;
    }
    if (lane == 63) wtot[wid] = incl;
    __syncthreads();
    unsigned int wexcl = 0u, total = 0u;
    #pragma unroll
    for (int w = 0; w < 16; ++w) { unsigned int t = wtot[w]; if (w < wid) wexcl += t; total += t; }
    unsigned int run = wexcl + (incl - s4);      // exclusive prefix over reversed buckets
    if (tid == 0) { T_s = 0; L_s = (int)total; } // defaults if total <= TOPK
    __syncthreads();                             // cnt reads (loc) done; defaults visible
    #pragma unroll
    for (int q = 0; q < 4; ++q) {
        int r = tid*4 + q;
        if (r < NB) {
            int bk = NB-1-r;
            unsigned int c = loc[q];
            if (run < TOPK && run + c >= TOPK) { T_s = bk; L_s = (int)(run + c); }  // unique crosser
            cnt[bk] = run;                       // overwrite count with start_desc
            run += c;
        }
    }
    __syncthreads();
    const int total_i = (int)total;
    int Treg = T_s;
    int regionEnd = L_s;

    // ---- scatter region 1 (buckets >= Treg only, ~TOPK writes) ----
    #pragma unroll
    for (int k = 0; k < KPT; ++k) {
        float s = sreg[k];
        if (s > 0.5f) {
            unsigned int bits = __float_as_uint(s);
            unsigned int bk = (bits >> 14) - BOFF;
            if (bk >= NB) bk = NB - 1;
            if ((int)bk >= Treg) {
                unsigned int pos = atomicAdd(&cnt[bk], 1u);
                lst[pos & LMASK] = ((u64)bits << 32) | (u64)(0xFFFFFFFFu - (unsigned int)(tid + (k<<10)));
            }
        }
    }
    __syncthreads();
    // scattered buckets: cnt[bk] = end_desc; start = cnt[bk+1] (or 0). unscattered: still start_desc.

    // ---- rank-and-permute region [0, regionEnd): slot = start + #{bucket-mates larger} ----
    {
        u64 kk[4]; int tt[4];
        #pragma unroll
        for (int i = 0; i < 4; ++i) {
            int p = tid + (i << 10);
            tt[i] = -1; kk[i] = 0ull;
            if (p < regionEnd) {
                u64 key = lst[p & LMASK];
                unsigned int bk = (unsigned int)(key >> 46) - BOFF;
                if (bk >= NB) bk = NB - 1;
                unsigned int st = (bk+1 < NB) ? cnt[bk+1] : 0u;
                unsigned int e  = cnt[bk];
                unsigned int rank = 0u;
                for (unsigned int q = st; q < e; ++q) rank += (lst[q & LMASK] > key) ? 1u : 0u;
                kk[i] = key; tt[i] = (int)(st + rank);
            }
        }
        __syncthreads();
        #pragma unroll
        for (int i = 0; i < 4; ++i) if (tt[i] >= 0) lst[tt[i] & LMASK] = kk[i];
        __syncthreads();
    }

    // ---- wave-parallel chunked scan ----
    int accN = 0;
    u64 key = 0ull; float4 bb = make_float4(0.f,0.f,0.f,0.f); float s = 0.f;
    if (lane < regionEnd) {
        key = lst[lane];
        unsigned int n = 0xFFFFFFFFu - (unsigned int)(key & 0xFFFFFFFFull);
        s = __uint_as_float((unsigned int)(key >> 32));
        bb = load_box(b13, b26, b52, b, (int)n);
    }

    int c = 0;
    while (c < total_i && accN < MAXB) {
        // ---- region extension (fallback; never taken for bench data) ----
        while (c + 64 > regionEnd && regionEnd < total_i) {
            int K2 = regionEnd + TOPK;
            if (tid == 0) { T_s = 0; L_s = total_i; }
            __syncthreads();
            for (int bk = tid; bk < Treg; bk += 1024) {
                unsigned int stv = cnt[bk];                                  // start_desc (untouched)
                unsigned int ev  = (bk == 0) ? (unsigned int)total_i : cnt[bk-1];  // end_desc[bk]
                if (stv < (unsigned int)K2 && ev >= (unsigned int)K2) { T_s = bk; L_s = (int)ev; }
            }
            __syncthreads();
            int T2 = T_s, L2 = L_s;
            #pragma unroll
            for (int k = 0; k < KPT; ++k) {
                float sv = sreg[k];
                if (sv > 0.5f) {
                    unsigned int bits = __float_as_uint(sv);
                    int bk = (int)((bits >> 14) - BOFF);
                    if (bk >= NB) bk = NB - 1;
                    if (bk >= T2 && bk < Treg) {
                        unsigned int pos = atomicAdd(&cnt[bk], 1u);
                        lst[pos & LMASK] = ((u64)bits << 32) | (u64)(0xFFFFFFFFu - (unsigned int)(tid + (k<<10)));
                    }
                }
            }
            __syncthreads();
            {
                u64 kk[4]; int tt[4];
                #pragma unroll
                for (int i = 0; i < 4; ++i) {
                    int p = regionEnd + tid + (i << 10);
                    tt[i] = -1; kk[i] = 0ull;
                    if (p < L2) {
                        u64 k2 = lst[p & LMASK];
                        unsigned int bk = (unsigned int)(k2 >> 46) - BOFF;
                        if (bk >= NB) bk = NB - 1;
                        unsigned int st = (bk+1 < NB) ? cnt[bk+1] : 0u;
                        unsigned int e  = cnt[bk];
                        unsigned int rank = 0u;
                        for (unsigned int q = st; q < e; ++q) rank += (lst[q & LMASK] > k2) ? 1u : 0u;
                        kk[i] = k2; tt[i] = (int)(st + rank);
                    }
                }
                __syncthreads();
                #pragma unroll
                for (int i = 0; i < 4; ++i) if (tt[i] >= 0) lst[tt[i] & LMASK] = kk[i];
                __syncthreads();
            }
            Treg = T2; regionEnd = L2;
            // reload current chunk (prefetched regs may be stale)
            key = 0ull; bb = make_float4(0.f,0.f,0.f,0.f); s = 0.f;
            if (c + lane < regionEnd) {
                key = lst[(c + lane) & LMASK];
                unsigned int n = 0xFFFFFFFFu - (unsigned int)(key & 0xFFFFFFFFull);
                s = __uint_as_float((unsigned int)(key >> 32));
                bb = load_box(b13, b26, b52, b, (int)n);
            }
        }

        int m = regionEnd - c; if (m > 64) m = 64;
        float oy1 = bb.x, ox1 = bb.y, oy2 = bb.z, ox2 = bb.w, cs = s;
        float y1 = fminf(oy1, oy2), y2 = fmaxf(oy1, oy2);
        float x1 = fminf(ox1, ox2), x2 = fmaxf(ox1, ox2);
        float ar = (y2-y1)*(x2-x1);

        // prefetch next chunk
        int nc = c + 64;
        if (nc + lane < regionEnd) {
            key = lst[(nc + lane) & LMASK];
            unsigned int n = 0xFFFFFFFFu - (unsigned int)(key & 0xFFFFFFFFull);
            s = __uint_as_float((unsigned int)(key >> 32));
            bb = load_box(b13, b26, b52, b, (int)n);
        } else { s = 0.f; bb = make_float4(0.f,0.f,0.f,0.f); }

        // --- wave w checks accepted slice {w, w+16, ...}; no break -> ds_reads pipeline ---
        bool supp = (lane >= m);
        #pragma unroll 2
        for (int j = wid; j < accN; j += 16) {
            float4 aj = acc4[j];                 // broadcast read, conflict-free
            float jar = (aj.z - aj.x) * (aj.w - aj.y);   // bit-identical to ref's area
            float iy1=fmaxf(y1,aj.x), iy2=fminf(y2,aj.z);
            float ix1=fmaxf(x1,aj.y), ix2=fminf(x2,aj.w);
            float inter=fmaxf(iy2-iy1,0.f)*fmaxf(ix2-ix1,0.f);
            float un=(ar+jar)-inter;
            supp |= (un > 0.f) && (inter/un > 0.5f);
        }
        u64 bal = __ballot(supp);
        if (lane == 0) sup_lds[wid] = bal;
        __syncthreads();

        // --- wave 0: lazy in-order resolve on the OR of all partial ballots ---
        if (wid == 0) {
            u64 B = 0ull;
            #pragma unroll
            for (int w = 0; w < 16; ++w) B |= sup_lds[w];
            u64 valid_m = (m >= 64) ? ~0ull : ((1ull << m) - 1ull);
            u64 rem = (~B) & valid_m;
            while (rem && accN < MAXB) {
                int j = __builtin_ctzll(rem);    // next in sorted order
                float jy1=__shfl(y1,j), jx1=__shfl(x1,j), jy2=__shfl(y2,j);
                float jx2=__shfl(x2,j), jar=__shfl(ar,j);
                if (lane == j) {                 // accepting lane appends its own record
                    acc4[accN] = make_float4(y1, x1, y2, x2);
                    outrec[accN][0]=fminf(fmaxf(oy1,0.f),1.f);
                    outrec[accN][1]=fminf(fmaxf(ox1,0.f),1.f);
                    outrec[accN][2]=fminf(fmaxf(oy2,0.f),1.f);
                    outrec[accN][3]=fminf(fmaxf(ox2,0.f),1.f);
                    outrec[accN][4]=cs;
                    outrec[accN][5]=0.f;
                }
                float iy1=fmaxf(y1,jy1), iy2=fminf(y2,jy2);
                float ix1=fmaxf(x1,jx1), ix2=fminf(x2,jx2);
                float inter=fmaxf(iy2-iy1,0.f)*fmaxf(ix2-ix1,0.f);
                float un=(ar+jar)-inter;
                bool kill = (un > 0.f) && (inter/un > 0.5f);
                rem &= ~__ballot(kill);
                rem &= ~(1ull << j);
                accN++;
            }
            if (lane == 0) accN_s = accN;
        }
        __syncthreads();
        accN = accN_s;
        c += 64;
    }

    // ---- block-wide output write ----
    const int accNf = accN_s;
    float* outp = out + (size_t)b * (MAXB*6);
    for (int i = tid; i < MAXB*6; i += 1024) {
        int t = i / 6;
        outp[i] = (t < accNf) ? outrec[t][i % 6] : 0.f;
    }
    if (tid == 0) out[(size_t)BATCH*(MAXB*6) + b] = (float)accNf;
}

extern "C" void kernel_launch(void* const* d_in, const int* in_sizes, int n_in,
                              void* d_out, int out_size, void* d_ws, size_t ws_size,
                              hipStream_t stream)
{
    const float* bbox13 = (const float*)d_in[0];
    const float* p13    = (const float*)d_in[1];
    const float* c13    = (const float*)d_in[2];
    const float* bbox26 = (const float*)d_in[3];
    const float* p26    = (const float*)d_in[4];
    const float* c26    = (const float*)d_in[5];
    const float* bbox52 = (const float*)d_in[6];
    const float* p52    = (const float*)d_in[7];
    const float* c52    = (const float*)d_in[8];
    float* out    = (float*)d_out;
    float* scores = (float*)d_ws;   // 64*10647*4 = 2.7 MB

    dim3 g1((NANCH + 255)/256, BATCH);
    score_kernel<<<g1, 256, 0, stream>>>(c13, p13, c26, p26, c52, p52, scores);
    nms_sort_scan<<<BATCH, 1024, 0, stream>>>(scores, bbox13, bbox26, bbox52, out);
}